// Round 2
// baseline (1757.756 us; speedup 1.0000x reference)
//
#include <hip/hip_runtime.h>

// ContrastiveGNN: 3x GCNConv(relu) + 2-layer projector MLP.
// N=100000 nodes, E=1600000 edges, IN_D=256, HID=OUT_D=64.

#define BLK 256

// ---------------- degree ----------------
__global__ void count_deg_kernel(const int* __restrict__ dst, float* __restrict__ deg, int E) {
    int e = blockIdx.x * BLK + threadIdx.x;
    if (e < E) atomicAdd(&deg[dst[e]], 1.0f);
}

__global__ void deg_finalize_kernel(float* __restrict__ deg_inv, float* __restrict__ deg_rs, int N) {
    int i = blockIdx.x * BLK + threadIdx.x;
    if (i < N) {
        float d = deg_inv[i] + 1.0f;   // +1 self loop
        deg_inv[i] = 1.0f / d;
        deg_rs[i]  = rsqrtf(d);
    }
}

// ---------------- GEMM: [N,256] x [256,64] -> [N,64] ----------------
__global__ void gemm_in256_kernel(const float* __restrict__ x, const float* __restrict__ W,
                                  float* __restrict__ h, int N) {
    __shared__ float xs[4][256];
    int row0 = blockIdx.x * 4;
    // cooperative load of 4 input rows (4x256 floats)
    for (int i = threadIdx.x; i < 4 * 256; i += BLK) {
        int rr = i >> 8, kk = i & 255;
        int grow = row0 + rr;
        xs[rr][kk] = (grow < N) ? x[(size_t)grow * 256 + kk] : 0.f;
    }
    __syncthreads();
    int col = threadIdx.x & 63;
    int r   = threadIdx.x >> 6;
    float acc = 0.f;
#pragma unroll 8
    for (int k = 0; k < 256; ++k) acc += xs[r][k] * W[k * 64 + col];
    int grow = row0 + r;
    if (grow < N) h[(size_t)grow * 64 + col] = acc;
}

// ---------------- GEMM: [N,64] x [64,64] -> [N,64]  (mode: 0=raw, 1=bias+relu, 2=bias) ----------------
template <int MODE>
__global__ void gemm64_kernel(const float* __restrict__ in, const float* __restrict__ W,
                              const float* __restrict__ b, float* __restrict__ out, int N) {
    __shared__ float Ws[64 * 64];
    __shared__ float xs[4][64];
    for (int i = threadIdx.x; i < 64 * 64; i += BLK) Ws[i] = W[i];
    int row0 = blockIdx.x * 4;
    {
        int i = threadIdx.x;           // 256 threads cover 4x64 exactly
        int rr = i >> 6, kk = i & 63;
        int grow = row0 + rr;
        xs[rr][kk] = (grow < N) ? in[(size_t)grow * 64 + kk] : 0.f;
    }
    __syncthreads();
    int col = threadIdx.x & 63;
    int r   = threadIdx.x >> 6;
    float acc = 0.f;
#pragma unroll
    for (int k = 0; k < 64; ++k) acc += xs[r][k] * Ws[k * 64 + col];
    int grow = row0 + r;
    if (grow < N) {
        size_t o = (size_t)grow * 64 + col;
        if (MODE == 1)      out[o] = fmaxf(acc + b[col], 0.f);
        else if (MODE == 2) out[o] = acc + b[col];
        else                out[o] = acc;
    }
}

// ---------------- edge scatter: agg[dst,f] += h[src,f] * drs[src]*drs[dst] ----------------
__global__ void scatter_kernel(const float* __restrict__ h, const int* __restrict__ src,
                               const int* __restrict__ dst, const float* __restrict__ drs,
                               float* __restrict__ agg, int E) {
    long long idx = (long long)blockIdx.x * BLK + threadIdx.x;
    long long e = idx >> 6;
    int f = (int)(idx & 63);
    if (e < E) {
        int s = src[e], d = dst[e];
        float nrm = drs[s] * drs[d];
        atomicAdd(&agg[(long long)d * 64 + f], h[(long long)s * 64 + f] * nrm);
    }
}

// ---------------- node finalize: out = relu(agg + h*deg_inv + b) ----------------
__global__ void node_finalize_kernel(const float* __restrict__ agg, const float* __restrict__ h,
                                     const float* __restrict__ deg_inv, const float* __restrict__ b,
                                     float* __restrict__ out, int N) {
    int idx = blockIdx.x * BLK + threadIdx.x;
    if (idx < N * 64) {
        int i = idx >> 6, f = idx & 63;
        float v = agg[idx] + h[idx] * deg_inv[i] + b[f];
        out[idx] = fmaxf(v, 0.f);
    }
}

extern "C" void kernel_launch(void* const* d_in, const int* in_sizes, int n_in,
                              void* d_out, int out_size, void* d_ws, size_t ws_size,
                              hipStream_t stream) {
    // inputs per setup_inputs() order
    const float* x   = (const float*)d_in[0];
    const float* W1  = (const float*)d_in[1];
    const float* b1  = (const float*)d_in[2];
    const float* W2  = (const float*)d_in[3];
    const float* b2  = (const float*)d_in[4];
    const float* W3  = (const float*)d_in[5];
    const float* b3  = (const float*)d_in[6];
    const float* Pw1 = (const float*)d_in[7];
    const float* Pb1 = (const float*)d_in[8];
    const float* Pw2 = (const float*)d_in[9];
    const float* Pb2 = (const float*)d_in[10];
    const int*   ei  = (const int*)d_in[11];

    const int N = in_sizes[0] / 256;
    const int E = in_sizes[11] / 2;
    const int* src = ei;
    const int* dst = ei + E;

    float* ws      = (float*)d_ws;
    float* deg_inv = ws;                       // N
    float* deg_rs  = ws + N;                   // N
    float* X       = ws + 2 * (size_t)N;       // N*64 (layer io)
    float* H       = X + (size_t)N * 64;       // N*64 (pre-agg h)
    float* AGG     = H + (size_t)N * 64;       // N*64

    const size_t featBytes = (size_t)N * 64 * sizeof(float);
    const int gNode  = (N + BLK - 1) / BLK;
    const int gRows  = (N + 3) / 4;
    const int gFeat  = (N * 64 + BLK - 1) / BLK;
    const int gEdge  = (E + BLK - 1) / BLK;
    const int gScat  = (int)(((long long)E * 64 + BLK - 1) / BLK);

    // degree (in-degree + 1)
    hipMemsetAsync(deg_inv, 0, (size_t)N * sizeof(float), stream);
    count_deg_kernel<<<gEdge, BLK, 0, stream>>>(dst, deg_inv, E);
    deg_finalize_kernel<<<gNode, BLK, 0, stream>>>(deg_inv, deg_rs, N);

    // ---- layer 1 ----
    gemm_in256_kernel<<<gRows, BLK, 0, stream>>>(x, W1, H, N);
    hipMemsetAsync(AGG, 0, featBytes, stream);
    scatter_kernel<<<gScat, BLK, 0, stream>>>(H, src, dst, deg_rs, AGG, E);
    node_finalize_kernel<<<gFeat, BLK, 0, stream>>>(AGG, H, deg_inv, b1, X, N);

    // ---- layer 2 ----
    gemm64_kernel<0><<<gRows, BLK, 0, stream>>>(X, W2, nullptr, H, N);
    hipMemsetAsync(AGG, 0, featBytes, stream);
    scatter_kernel<<<gScat, BLK, 0, stream>>>(H, src, dst, deg_rs, AGG, E);
    node_finalize_kernel<<<gFeat, BLK, 0, stream>>>(AGG, H, deg_inv, b2, X, N);

    // ---- layer 3 ----
    gemm64_kernel<0><<<gRows, BLK, 0, stream>>>(X, W3, nullptr, H, N);
    hipMemsetAsync(AGG, 0, featBytes, stream);
    scatter_kernel<<<gScat, BLK, 0, stream>>>(H, src, dst, deg_rs, AGG, E);
    node_finalize_kernel<<<gFeat, BLK, 0, stream>>>(AGG, H, deg_inv, b3, X, N);

    // ---- projector ----
    gemm64_kernel<1><<<gRows, BLK, 0, stream>>>(X, Pw1, Pb1, H, N);
    gemm64_kernel<2><<<gRows, BLK, 0, stream>>>(H, Pw2, Pb2, (float*)d_out, N);
}

// Round 3
// 970.912 us; speedup vs baseline: 1.8104x; 1.8104x over previous
//
#include <hip/hip_runtime.h>

// ContrastiveGNN: 3x GCNConv(relu) + 2-layer projector MLP.
// N=100000 nodes, E=1600000 edges, IN_D=256, HID=OUT_D=64.
// Round 3: atomic scatter -> device-built CSR + register gather-aggregate
// with fused self-loop+bias+relu epilogue.

#define BLK 256
#define SCAN_CHUNK 1024

// ---------------- degree (int histogram) ----------------
__global__ void count_deg_kernel(const int* __restrict__ dst, int* __restrict__ deg_cnt, int E) {
    int e = blockIdx.x * BLK + threadIdx.x;
    if (e < E) atomicAdd(&deg_cnt[dst[e]], 1);
}

__global__ void deg_finalize_kernel(const int* __restrict__ deg_cnt,
                                    float* __restrict__ deg_inv, float* __restrict__ deg_rs, int N) {
    int i = blockIdx.x * BLK + threadIdx.x;
    if (i < N) {
        float d = (float)deg_cnt[i] + 1.0f;   // +1 self loop
        deg_inv[i] = 1.0f / d;
        deg_rs[i]  = rsqrtf(d);
    }
}

// ---------------- exclusive scan of deg_cnt -> rowptr (3 kernels) ----------------
__global__ void scan_reduce_kernel(const int* __restrict__ cnt, int* __restrict__ bsum, int N) {
    __shared__ int red[BLK];
    int base = blockIdx.x * SCAN_CHUNK;
    int s = 0;
    for (int i = threadIdx.x; i < SCAN_CHUNK; i += BLK) {
        int g = base + i;
        s += (g < N) ? cnt[g] : 0;
    }
    red[threadIdx.x] = s;
    __syncthreads();
    for (int off = BLK / 2; off > 0; off >>= 1) {
        if (threadIdx.x < off) red[threadIdx.x] += red[threadIdx.x + off];
        __syncthreads();
    }
    if (threadIdx.x == 0) bsum[blockIdx.x] = red[0];
}

__global__ void scan_top_kernel(int* __restrict__ bsum, int NB) {
    if (blockIdx.x == 0 && threadIdx.x == 0) {
        int acc = 0;
        for (int i = 0; i < NB; ++i) { int v = bsum[i]; bsum[i] = acc; acc += v; }
    }
}

__global__ void scan_final_kernel(const int* __restrict__ cnt, const int* __restrict__ bsum,
                                  int* __restrict__ rowptr, int* __restrict__ cursor, int N, int E) {
    __shared__ int ts[BLK];
    int base = blockIdx.x * SCAN_CHUNK;
    int tb = base + threadIdx.x * 4;
    int v[4];
    int mySum = 0;
#pragma unroll
    for (int j = 0; j < 4; ++j) {
        int g = tb + j;
        v[j] = (g < N) ? cnt[g] : 0;
        mySum += v[j];
    }
    ts[threadIdx.x] = mySum;
    __syncthreads();
    for (int off = 1; off < BLK; off <<= 1) {
        int t = (threadIdx.x >= off) ? ts[threadIdx.x - off] : 0;
        __syncthreads();
        ts[threadIdx.x] += t;
        __syncthreads();
    }
    int excl = ts[threadIdx.x] - mySum + bsum[blockIdx.x];
#pragma unroll
    for (int j = 0; j < 4; ++j) {
        int g = tb + j;
        if (g < N) { rowptr[g] = excl; cursor[g] = excl; }
        excl += v[j];
    }
    if (blockIdx.x == 0 && threadIdx.x == 0) rowptr[N] = E;
}

// ---------------- CSR fill: bucket edges by dst, precompute src weight ----------------
__global__ void csr_fill_kernel(const int* __restrict__ src, const int* __restrict__ dst,
                                const float* __restrict__ deg_rs,
                                int* __restrict__ cursor, int* __restrict__ csr_src,
                                float* __restrict__ csr_w, int E) {
    int e = blockIdx.x * BLK + threadIdx.x;
    if (e < E) {
        int s = src[e], d = dst[e];
        int pos = atomicAdd(&cursor[d], 1);
        csr_src[pos] = s;
        csr_w[pos]   = deg_rs[s];
    }
}

// ---------------- GEMM: [N,256] x [256,64] -> [N,64] ----------------
__global__ void gemm_in256_kernel(const float* __restrict__ x, const float* __restrict__ W,
                                  float* __restrict__ h, int N) {
    __shared__ float xs[4][256];
    int row0 = blockIdx.x * 4;
    for (int i = threadIdx.x; i < 4 * 256; i += BLK) {
        int rr = i >> 8, kk = i & 255;
        int grow = row0 + rr;
        xs[rr][kk] = (grow < N) ? x[(size_t)grow * 256 + kk] : 0.f;
    }
    __syncthreads();
    int col = threadIdx.x & 63;
    int r   = threadIdx.x >> 6;
    float acc = 0.f;
#pragma unroll 8
    for (int k = 0; k < 256; ++k) acc += xs[r][k] * W[k * 64 + col];
    int grow = row0 + r;
    if (grow < N) h[(size_t)grow * 64 + col] = acc;
}

// ---------------- GEMM: [N,64] x [64,64] -> [N,64]  (mode: 0=raw, 1=bias+relu, 2=bias) ----------------
template <int MODE>
__global__ void gemm64_kernel(const float* __restrict__ in, const float* __restrict__ W,
                              const float* __restrict__ b, float* __restrict__ out, int N) {
    __shared__ float Ws[64 * 64];
    __shared__ float xs[4][64];
    for (int i = threadIdx.x; i < 64 * 64; i += BLK) Ws[i] = W[i];
    int row0 = blockIdx.x * 4;
    {
        int i = threadIdx.x;
        int rr = i >> 6, kk = i & 63;
        int grow = row0 + rr;
        xs[rr][kk] = (grow < N) ? in[(size_t)grow * 64 + kk] : 0.f;
    }
    __syncthreads();
    int col = threadIdx.x & 63;
    int r   = threadIdx.x >> 6;
    float acc = 0.f;
#pragma unroll
    for (int k = 0; k < 64; ++k) acc += xs[r][k] * Ws[k * 64 + col];
    int grow = row0 + r;
    if (grow < N) {
        size_t o = (size_t)grow * 64 + col;
        if (MODE == 1)      out[o] = fmaxf(acc + b[col], 0.f);
        else if (MODE == 2) out[o] = acc + b[col];
        else                out[o] = acc;
    }
}

// ---------------- gather-aggregate + fused epilogue ----------------
// One wave per node, lane = feature. out = relu(drs[d]*sum(w_s*h[s]) + h[d]*dinv[d] + b)
__global__ void gcn_gather_kernel(const float* __restrict__ h,
                                  const int* __restrict__ rowptr,
                                  const int* __restrict__ csr_src,
                                  const float* __restrict__ csr_w,
                                  const float* __restrict__ deg_rs,
                                  const float* __restrict__ deg_inv,
                                  const float* __restrict__ b,
                                  float* __restrict__ out, int N) {
    int node = blockIdx.x * 4 + (threadIdx.x >> 6);
    int f    = threadIdx.x & 63;
    if (node >= N) return;
    int beg = rowptr[node], end = rowptr[node + 1];
    float acc = 0.f;
    int i = beg;
    for (; i + 4 <= end; i += 4) {
        int   s0 = csr_src[i],     s1 = csr_src[i + 1];
        int   s2 = csr_src[i + 2], s3 = csr_src[i + 3];
        float w0 = csr_w[i],       w1 = csr_w[i + 1];
        float w2 = csr_w[i + 2],   w3 = csr_w[i + 3];
        acc += h[s0 * 64 + f] * w0;
        acc += h[s1 * 64 + f] * w1;
        acc += h[s2 * 64 + f] * w2;
        acc += h[s3 * 64 + f] * w3;
    }
    for (; i < end; ++i) {
        int s = csr_src[i];
        acc += h[s * 64 + f] * csr_w[i];
    }
    float res = acc * deg_rs[node] + h[node * 64 + f] * deg_inv[node] + b[f];
    out[node * 64 + f] = fmaxf(res, 0.f);
}

extern "C" void kernel_launch(void* const* d_in, const int* in_sizes, int n_in,
                              void* d_out, int out_size, void* d_ws, size_t ws_size,
                              hipStream_t stream) {
    const float* x   = (const float*)d_in[0];
    const float* W1  = (const float*)d_in[1];
    const float* b1  = (const float*)d_in[2];
    const float* W2  = (const float*)d_in[3];
    const float* b2  = (const float*)d_in[4];
    const float* W3  = (const float*)d_in[5];
    const float* b3  = (const float*)d_in[6];
    const float* Pw1 = (const float*)d_in[7];
    const float* Pb1 = (const float*)d_in[8];
    const float* Pw2 = (const float*)d_in[9];
    const float* Pb2 = (const float*)d_in[10];
    const int*   ei  = (const int*)d_in[11];

    const int N = in_sizes[0] / 256;
    const int E = in_sizes[11] / 2;
    const int* src = ei;
    const int* dst = ei + E;

    // workspace layout (all 4-byte types)
    char* p = (char*)d_ws;
    float* deg_inv = (float*)p;                 p += (size_t)N * 4;
    float* deg_rs  = (float*)p;                 p += (size_t)N * 4;
    float* X       = (float*)p;                 p += (size_t)N * 64 * 4;
    float* H       = (float*)p;                 p += (size_t)N * 64 * 4;
    int*   deg_cnt = (int*)p;                   p += (size_t)N * 4;
    int*   rowptr  = (int*)p;                   p += ((size_t)N + 1) * 4;
    int*   cursor  = (int*)p;                   p += (size_t)N * 4;
    int*   bsum    = (int*)p;                   p += 128 * 4;
    int*   csr_src = (int*)p;                   p += (size_t)E * 4;
    float* csr_w   = (float*)p;                 p += (size_t)E * 4;

    const int gNode = (N + BLK - 1) / BLK;
    const int gRows = (N + 3) / 4;
    const int gEdge = (E + BLK - 1) / BLK;
    const int NB    = (N + SCAN_CHUNK - 1) / SCAN_CHUNK;

    // ---- degree + CSR build ----
    hipMemsetAsync(deg_cnt, 0, (size_t)N * sizeof(int), stream);
    count_deg_kernel<<<gEdge, BLK, 0, stream>>>(dst, deg_cnt, E);
    deg_finalize_kernel<<<gNode, BLK, 0, stream>>>(deg_cnt, deg_inv, deg_rs, N);
    scan_reduce_kernel<<<NB, BLK, 0, stream>>>(deg_cnt, bsum, N);
    scan_top_kernel<<<1, BLK, 0, stream>>>(bsum, NB);
    scan_final_kernel<<<NB, BLK, 0, stream>>>(deg_cnt, bsum, rowptr, cursor, N, E);
    csr_fill_kernel<<<gEdge, BLK, 0, stream>>>(src, dst, deg_rs, cursor, csr_src, csr_w, E);

    // ---- layer 1 ----
    gemm_in256_kernel<<<gRows, BLK, 0, stream>>>(x, W1, H, N);
    gcn_gather_kernel<<<gRows, BLK, 0, stream>>>(H, rowptr, csr_src, csr_w, deg_rs, deg_inv, b1, X, N);

    // ---- layer 2 ----
    gemm64_kernel<0><<<gRows, BLK, 0, stream>>>(X, W2, nullptr, H, N);
    gcn_gather_kernel<<<gRows, BLK, 0, stream>>>(H, rowptr, csr_src, csr_w, deg_rs, deg_inv, b2, X, N);

    // ---- layer 3 ----
    gemm64_kernel<0><<<gRows, BLK, 0, stream>>>(X, W3, nullptr, H, N);
    gcn_gather_kernel<<<gRows, BLK, 0, stream>>>(H, rowptr, csr_src, csr_w, deg_rs, deg_inv, b3, X, N);

    // ---- projector ----
    gemm64_kernel<1><<<gRows, BLK, 0, stream>>>(X, Pw1, Pb1, H, N);
    gemm64_kernel<2><<<gRows, BLK, 0, stream>>>(H, Pw2, Pb2, (float*)d_out, N);
}

// Round 5
// 869.016 us; speedup vs baseline: 2.0227x; 1.1173x over previous
//
#include <hip/hip_runtime.h>

// ContrastiveGNN: 3x GCNConv(relu) + 2-layer projector MLP.
// N=100000 nodes, E=1600000 edges, IN_D=256, HID=OUT_D=64.
// Round 4 (resubmit): GEMMs restructured as row-blocked scalar-operand GEMMs
// (wave = 8 rows x 64 cols; x-rows via wave-uniform scalar loads,
// one vector W dword per k shared across 8 rows).

#define BLK 256
#define SCAN_CHUNK 1024

// ---------------- degree (int histogram) ----------------
__global__ void count_deg_kernel(const int* __restrict__ dst, int* __restrict__ deg_cnt, int E) {
    int e = blockIdx.x * BLK + threadIdx.x;
    if (e < E) atomicAdd(&deg_cnt[dst[e]], 1);
}

__global__ void deg_finalize_kernel(const int* __restrict__ deg_cnt,
                                    float* __restrict__ deg_inv, float* __restrict__ deg_rs, int N) {
    int i = blockIdx.x * BLK + threadIdx.x;
    if (i < N) {
        float d = (float)deg_cnt[i] + 1.0f;   // +1 self loop
        deg_inv[i] = 1.0f / d;
        deg_rs[i]  = rsqrtf(d);
    }
}

// ---------------- exclusive scan of deg_cnt -> rowptr (3 kernels) ----------------
__global__ void scan_reduce_kernel(const int* __restrict__ cnt, int* __restrict__ bsum, int N) {
    __shared__ int red[BLK];
    int base = blockIdx.x * SCAN_CHUNK;
    int s = 0;
    for (int i = threadIdx.x; i < SCAN_CHUNK; i += BLK) {
        int g = base + i;
        s += (g < N) ? cnt[g] : 0;
    }
    red[threadIdx.x] = s;
    __syncthreads();
    for (int off = BLK / 2; off > 0; off >>= 1) {
        if (threadIdx.x < off) red[threadIdx.x] += red[threadIdx.x + off];
        __syncthreads();
    }
    if (threadIdx.x == 0) bsum[blockIdx.x] = red[0];
}

__global__ void scan_top_kernel(int* __restrict__ bsum, int NB) {
    if (blockIdx.x == 0 && threadIdx.x == 0) {
        int acc = 0;
        for (int i = 0; i < NB; ++i) { int v = bsum[i]; bsum[i] = acc; acc += v; }
    }
}

__global__ void scan_final_kernel(const int* __restrict__ cnt, const int* __restrict__ bsum,
                                  int* __restrict__ rowptr, int* __restrict__ cursor, int N, int E) {
    __shared__ int ts[BLK];
    int base = blockIdx.x * SCAN_CHUNK;
    int tb = base + threadIdx.x * 4;
    int v[4];
    int mySum = 0;
#pragma unroll
    for (int j = 0; j < 4; ++j) {
        int g = tb + j;
        v[j] = (g < N) ? cnt[g] : 0;
        mySum += v[j];
    }
    ts[threadIdx.x] = mySum;
    __syncthreads();
    for (int off = 1; off < BLK; off <<= 1) {
        int t = (threadIdx.x >= off) ? ts[threadIdx.x - off] : 0;
        __syncthreads();
        ts[threadIdx.x] += t;
        __syncthreads();
    }
    int excl = ts[threadIdx.x] - mySum + bsum[blockIdx.x];
#pragma unroll
    for (int j = 0; j < 4; ++j) {
        int g = tb + j;
        if (g < N) { rowptr[g] = excl; cursor[g] = excl; }
        excl += v[j];
    }
    if (blockIdx.x == 0 && threadIdx.x == 0) rowptr[N] = E;
}

// ---------------- CSR fill: bucket edges by dst, precompute src weight ----------------
__global__ void csr_fill_kernel(const int* __restrict__ src, const int* __restrict__ dst,
                                const float* __restrict__ deg_rs,
                                int* __restrict__ cursor, int* __restrict__ csr_src,
                                float* __restrict__ csr_w, int E) {
    int e = blockIdx.x * BLK + threadIdx.x;
    if (e < E) {
        int s = src[e], d = dst[e];
        int pos = atomicAdd(&cursor[d], 1);
        csr_src[pos] = s;
        csr_w[pos]   = deg_rs[s];
    }
}

// ---------------- row-blocked scalar-operand GEMM ----------------
// [N,K] x [K,64] -> [N,64]. 256 threads = 4 waves; each wave computes
// 8 rows x 64 cols (lane = col). Row base made wave-uniform via
// readfirstlane so x-row float4 loads compile to s_load_dwordx4;
// per-k the only VMEM op is one W dword shared by all 8 rows.
// MODE: 0=raw, 1=bias+relu, 2=bias
template <int K, int MODE>
__global__ void gemm_rows_kernel(const float* __restrict__ x, const float* __restrict__ W,
                                 const float* __restrict__ b, float* __restrict__ out, int N) {
    const int lane = threadIdx.x & 63;
    const int wid  = threadIdx.x >> 6;
    int row0 = blockIdx.x * 32 + wid * 8;
    row0 = __builtin_amdgcn_readfirstlane(row0);

    // uniform per-row base pointers (SGPR pairs); clamp for tail safety
    const float* xr[8];
#pragma unroll
    for (int j = 0; j < 8; ++j) {
        int r = row0 + j;
        if (r >= N) r = N - 1;
        xr[j] = x + (size_t)r * K;
    }

    float acc[8] = {0.f, 0.f, 0.f, 0.f, 0.f, 0.f, 0.f, 0.f};

    for (int k0 = 0; k0 < K; k0 += 4) {
        float w0 = W[(k0 + 0) * 64 + lane];
        float w1 = W[(k0 + 1) * 64 + lane];
        float w2 = W[(k0 + 2) * 64 + lane];
        float w3 = W[(k0 + 3) * 64 + lane];
#pragma unroll
        for (int j = 0; j < 8; ++j) {
            const float4 xv = *(const float4*)(xr[j] + k0);
            acc[j] = fmaf(xv.x, w0, acc[j]);
            acc[j] = fmaf(xv.y, w1, acc[j]);
            acc[j] = fmaf(xv.z, w2, acc[j]);
            acc[j] = fmaf(xv.w, w3, acc[j]);
        }
    }

    float bias = (MODE != 0) ? b[lane] : 0.f;
#pragma unroll
    for (int j = 0; j < 8; ++j) {
        int r = row0 + j;
        if (r < N) {
            float v = acc[j] + bias;
            if (MODE == 1) v = fmaxf(v, 0.f);
            out[(size_t)r * 64 + lane] = v;
        }
    }
}

// ---------------- gather-aggregate + fused epilogue ----------------
// One wave per node, lane = feature. out = relu(drs[d]*sum(w_s*h[s]) + h[d]*dinv[d] + b)
__global__ void gcn_gather_kernel(const float* __restrict__ h,
                                  const int* __restrict__ rowptr,
                                  const int* __restrict__ csr_src,
                                  const float* __restrict__ csr_w,
                                  const float* __restrict__ deg_rs,
                                  const float* __restrict__ deg_inv,
                                  const float* __restrict__ b,
                                  float* __restrict__ out, int N) {
    int node = blockIdx.x * 4 + (threadIdx.x >> 6);
    int f    = threadIdx.x & 63;
    if (node >= N) return;
    int beg = rowptr[node], end = rowptr[node + 1];
    float acc = 0.f;
    int i = beg;
    for (; i + 4 <= end; i += 4) {
        int   s0 = csr_src[i],     s1 = csr_src[i + 1];
        int   s2 = csr_src[i + 2], s3 = csr_src[i + 3];
        float w0 = csr_w[i],       w1 = csr_w[i + 1];
        float w2 = csr_w[i + 2],   w3 = csr_w[i + 3];
        acc += h[s0 * 64 + f] * w0;
        acc += h[s1 * 64 + f] * w1;
        acc += h[s2 * 64 + f] * w2;
        acc += h[s3 * 64 + f] * w3;
    }
    for (; i < end; ++i) {
        int s = csr_src[i];
        acc += h[s * 64 + f] * csr_w[i];
    }
    float res = acc * deg_rs[node] + h[node * 64 + f] * deg_inv[node] + b[f];
    out[node * 64 + f] = fmaxf(res, 0.f);
}

extern "C" void kernel_launch(void* const* d_in, const int* in_sizes, int n_in,
                              void* d_out, int out_size, void* d_ws, size_t ws_size,
                              hipStream_t stream) {
    const float* x   = (const float*)d_in[0];
    const float* W1  = (const float*)d_in[1];
    const float* b1  = (const float*)d_in[2];
    const float* W2  = (const float*)d_in[3];
    const float* b2  = (const float*)d_in[4];
    const float* W3  = (const float*)d_in[5];
    const float* b3  = (const float*)d_in[6];
    const float* Pw1 = (const float*)d_in[7];
    const float* Pb1 = (const float*)d_in[8];
    const float* Pw2 = (const float*)d_in[9];
    const float* Pb2 = (const float*)d_in[10];
    const int*   ei  = (const int*)d_in[11];

    const int N = in_sizes[0] / 256;
    const int E = in_sizes[11] / 2;
    const int* src = ei;
    const int* dst = ei + E;

    // workspace layout (all 4-byte types)
    char* p = (char*)d_ws;
    float* deg_inv = (float*)p;                 p += (size_t)N * 4;
    float* deg_rs  = (float*)p;                 p += (size_t)N * 4;
    float* X       = (float*)p;                 p += (size_t)N * 64 * 4;
    float* H       = (float*)p;                 p += (size_t)N * 64 * 4;
    int*   deg_cnt = (int*)p;                   p += (size_t)N * 4;
    int*   rowptr  = (int*)p;                   p += ((size_t)N + 1) * 4;
    int*   cursor  = (int*)p;                   p += (size_t)N * 4;
    int*   bsum    = (int*)p;                   p += 128 * 4;
    int*   csr_src = (int*)p;                   p += (size_t)E * 4;
    float* csr_w   = (float*)p;                 p += (size_t)E * 4;

    const int gNode = (N + BLK - 1) / BLK;
    const int gRows = (N + 3) / 4;        // gather: 4 nodes/block
    const int gGemm = (N + 31) / 32;      // gemm: 32 rows/block
    const int gEdge = (E + BLK - 1) / BLK;
    const int NB    = (N + SCAN_CHUNK - 1) / SCAN_CHUNK;

    // ---- degree + CSR build ----
    hipMemsetAsync(deg_cnt, 0, (size_t)N * sizeof(int), stream);
    count_deg_kernel<<<gEdge, BLK, 0, stream>>>(dst, deg_cnt, E);
    deg_finalize_kernel<<<gNode, BLK, 0, stream>>>(deg_cnt, deg_inv, deg_rs, N);
    scan_reduce_kernel<<<NB, BLK, 0, stream>>>(deg_cnt, bsum, N);
    scan_top_kernel<<<1, BLK, 0, stream>>>(bsum, NB);
    scan_final_kernel<<<NB, BLK, 0, stream>>>(deg_cnt, bsum, rowptr, cursor, N, E);
    csr_fill_kernel<<<gEdge, BLK, 0, stream>>>(src, dst, deg_rs, cursor, csr_src, csr_w, E);

    // ---- layer 1 ----
    gemm_rows_kernel<256, 0><<<gGemm, BLK, 0, stream>>>(x, W1, nullptr, H, N);
    gcn_gather_kernel<<<gRows, BLK, 0, stream>>>(H, rowptr, csr_src, csr_w, deg_rs, deg_inv, b1, X, N);

    // ---- layer 2 ----
    gemm_rows_kernel<64, 0><<<gGemm, BLK, 0, stream>>>(X, W2, nullptr, H, N);
    gcn_gather_kernel<<<gRows, BLK, 0, stream>>>(H, rowptr, csr_src, csr_w, deg_rs, deg_inv, b2, X, N);

    // ---- layer 3 ----
    gemm_rows_kernel<64, 0><<<gGemm, BLK, 0, stream>>>(X, W3, nullptr, H, N);
    gcn_gather_kernel<<<gRows, BLK, 0, stream>>>(H, rowptr, csr_src, csr_w, deg_rs, deg_inv, b3, X, N);

    // ---- projector ----
    gemm_rows_kernel<64, 1><<<gGemm, BLK, 0, stream>>>(X, Pw1, Pb1, H, N);
    gemm_rows_kernel<64, 2><<<gGemm, BLK, 0, stream>>>(H, Pw2, Pb2, (float*)d_out, N);
}

// Round 6
// 742.150 us; speedup vs baseline: 2.3685x; 1.1709x over previous
//
#include <hip/hip_runtime.h>

// ContrastiveGNN: 3x GCNConv(relu) + 2-layer projector MLP.
// N=100000 nodes, E=1600000 edges, IN_D=256, HID=OUT_D=64.
// Round 6: GEMM redesigned — x streamed through LDS (vector path, coalesced),
// W through scalar loads (uniform, K$-resident). 32 FMAs per LDS read.

#define BLK 256
#define SCAN_CHUNK 1024

// ---------------- degree (int histogram) ----------------
__global__ void count_deg_kernel(const int* __restrict__ dst, int* __restrict__ deg_cnt, int E) {
    int e = blockIdx.x * BLK + threadIdx.x;
    if (e < E) atomicAdd(&deg_cnt[dst[e]], 1);
}

__global__ void deg_finalize_kernel(const int* __restrict__ deg_cnt,
                                    float* __restrict__ deg_inv, float* __restrict__ deg_rs, int N) {
    int i = blockIdx.x * BLK + threadIdx.x;
    if (i < N) {
        float d = (float)deg_cnt[i] + 1.0f;   // +1 self loop
        deg_inv[i] = 1.0f / d;
        deg_rs[i]  = rsqrtf(d);
    }
}

// ---------------- exclusive scan of deg_cnt -> rowptr (3 kernels) ----------------
__global__ void scan_reduce_kernel(const int* __restrict__ cnt, int* __restrict__ bsum, int N) {
    __shared__ int red[BLK];
    int base = blockIdx.x * SCAN_CHUNK;
    int s = 0;
    for (int i = threadIdx.x; i < SCAN_CHUNK; i += BLK) {
        int g = base + i;
        s += (g < N) ? cnt[g] : 0;
    }
    red[threadIdx.x] = s;
    __syncthreads();
    for (int off = BLK / 2; off > 0; off >>= 1) {
        if (threadIdx.x < off) red[threadIdx.x] += red[threadIdx.x + off];
        __syncthreads();
    }
    if (threadIdx.x == 0) bsum[blockIdx.x] = red[0];
}

__global__ void scan_top_kernel(int* __restrict__ bsum, int NB) {
    if (blockIdx.x == 0 && threadIdx.x == 0) {
        int acc = 0;
        for (int i = 0; i < NB; ++i) { int v = bsum[i]; bsum[i] = acc; acc += v; }
    }
}

__global__ void scan_final_kernel(const int* __restrict__ cnt, const int* __restrict__ bsum,
                                  int* __restrict__ rowptr, int* __restrict__ cursor, int N, int E) {
    __shared__ int ts[BLK];
    int base = blockIdx.x * SCAN_CHUNK;
    int tb = base + threadIdx.x * 4;
    int v[4];
    int mySum = 0;
#pragma unroll
    for (int j = 0; j < 4; ++j) {
        int g = tb + j;
        v[j] = (g < N) ? cnt[g] : 0;
        mySum += v[j];
    }
    ts[threadIdx.x] = mySum;
    __syncthreads();
    for (int off = 1; off < BLK; off <<= 1) {
        int t = (threadIdx.x >= off) ? ts[threadIdx.x - off] : 0;
        __syncthreads();
        ts[threadIdx.x] += t;
        __syncthreads();
    }
    int excl = ts[threadIdx.x] - mySum + bsum[blockIdx.x];
#pragma unroll
    for (int j = 0; j < 4; ++j) {
        int g = tb + j;
        if (g < N) { rowptr[g] = excl; cursor[g] = excl; }
        excl += v[j];
    }
    if (blockIdx.x == 0 && threadIdx.x == 0) rowptr[N] = E;
}

// ---------------- CSR fill: bucket edges by dst, precompute src weight ----------------
__global__ void csr_fill_kernel(const int* __restrict__ src, const int* __restrict__ dst,
                                const float* __restrict__ deg_rs,
                                int* __restrict__ cursor, int* __restrict__ csr_src,
                                float* __restrict__ csr_w, int E) {
    int e = blockIdx.x * BLK + threadIdx.x;
    if (e < E) {
        int s = src[e], d = dst[e];
        int pos = atomicAdd(&cursor[d], 1);
        csr_src[pos] = s;
        csr_w[pos]   = deg_rs[s];
    }
}

// ---------------- LDS-staged GEMM: [N,K] x [K,64] -> [N,64] ----------------
// 256 threads = 128 rows x 2 col-halves. x chunk (128 x 64) staged in LDS
// with pad-65 stride (column reads = 2 lanes/bank, conflict-free).
// W row values are wave-uniform -> scalar loads (K$-resident, W <= 64 KB).
// Per k per thread: 1 ds_read_b32 + 32 v_fmac (SGPR W operand).
// MODE: 0=raw, 1=bias+relu, 2=bias
template <int K, int MODE>
__global__ __launch_bounds__(256) void gemm_lds_kernel(const float* __restrict__ x,
                                                       const float* __restrict__ W,
                                                       const float* __restrict__ b,
                                                       float* __restrict__ out, int N) {
    constexpr int KC = 64;   // k-chunk
    __shared__ float xs[128 * 65];   // 33.3 KB
    const int tid  = threadIdx.x;
    const int row  = tid & 127;
    const int half = __builtin_amdgcn_readfirstlane(threadIdx.x >> 7);  // 0/1, wave-uniform
    const int row0 = blockIdx.x * 128;

    float acc[32];
#pragma unroll
    for (int c = 0; c < 32; ++c) acc[c] = 0.f;

    for (int kc = 0; kc < K; kc += KC) {
        __syncthreads();   // protect xs from previous chunk's readers
        // stage x[row0..row0+127][kc..kc+63] (coalesced float4 per 8-lane group)
#pragma unroll
        for (int i = 0; i < 8; ++i) {
            int q  = i * 256 + tid;          // float4 index in [0, 2048)
            int r  = q >> 4;                 // 16 float4 per row
            int j4 = q & 15;
            int gr = row0 + r; if (gr >= N) gr = N - 1;
            const float4 v = *(const float4*)(x + (size_t)gr * K + kc + j4 * 4);
            float* d = &xs[r * 65 + j4 * 4];
            d[0] = v.x; d[1] = v.y; d[2] = v.z; d[3] = v.w;
        }
        __syncthreads();

        const float* Wbase = W + (size_t)kc * 64 + half * 32;
#pragma unroll 2
        for (int k = 0; k < KC; ++k) {
            float xv = xs[row * 65 + k];
            const float* Wr = Wbase + (size_t)k * 64;   // uniform -> s_load
#pragma unroll
            for (int c = 0; c < 32; ++c) acc[c] = fmaf(xv, Wr[c], acc[c]);
        }
    }

    int gr = row0 + row;
    if (gr < N) {
        float* o = out + (size_t)gr * 64 + half * 32;
#pragma unroll
        for (int c = 0; c < 32; ++c) {
            float v = acc[c] + ((MODE != 0) ? b[half * 32 + c] : 0.f);
            if (MODE == 1) v = fmaxf(v, 0.f);
            o[c] = v;
        }
    }
}

// ---------------- gather-aggregate + fused epilogue ----------------
// One wave per node, lane = feature. out = relu(drs[d]*sum(w_s*h[s]) + h[d]*dinv[d] + b)
__global__ void gcn_gather_kernel(const float* __restrict__ h,
                                  const int* __restrict__ rowptr,
                                  const int* __restrict__ csr_src,
                                  const float* __restrict__ csr_w,
                                  const float* __restrict__ deg_rs,
                                  const float* __restrict__ deg_inv,
                                  const float* __restrict__ b,
                                  float* __restrict__ out, int N) {
    int node = blockIdx.x * 4 + (threadIdx.x >> 6);
    int f    = threadIdx.x & 63;
    if (node >= N) return;
    int beg = rowptr[node], end = rowptr[node + 1];
    float acc = 0.f;
    int i = beg;
    for (; i + 4 <= end; i += 4) {
        int   s0 = csr_src[i],     s1 = csr_src[i + 1];
        int   s2 = csr_src[i + 2], s3 = csr_src[i + 3];
        float w0 = csr_w[i],       w1 = csr_w[i + 1];
        float w2 = csr_w[i + 2],   w3 = csr_w[i + 3];
        acc += h[s0 * 64 + f] * w0;
        acc += h[s1 * 64 + f] * w1;
        acc += h[s2 * 64 + f] * w2;
        acc += h[s3 * 64 + f] * w3;
    }
    for (; i < end; ++i) {
        int s = csr_src[i];
        acc += h[s * 64 + f] * csr_w[i];
    }
    float res = acc * deg_rs[node] + h[node * 64 + f] * deg_inv[node] + b[f];
    out[node * 64 + f] = fmaxf(res, 0.f);
}

extern "C" void kernel_launch(void* const* d_in, const int* in_sizes, int n_in,
                              void* d_out, int out_size, void* d_ws, size_t ws_size,
                              hipStream_t stream) {
    const float* x   = (const float*)d_in[0];
    const float* W1  = (const float*)d_in[1];
    const float* b1  = (const float*)d_in[2];
    const float* W2  = (const float*)d_in[3];
    const float* b2  = (const float*)d_in[4];
    const float* W3  = (const float*)d_in[5];
    const float* b3  = (const float*)d_in[6];
    const float* Pw1 = (const float*)d_in[7];
    const float* Pb1 = (const float*)d_in[8];
    const float* Pw2 = (const float*)d_in[9];
    const float* Pb2 = (const float*)d_in[10];
    const int*   ei  = (const int*)d_in[11];

    const int N = in_sizes[0] / 256;
    const int E = in_sizes[11] / 2;
    const int* src = ei;
    const int* dst = ei + E;

    // workspace layout (all 4-byte types)
    char* p = (char*)d_ws;
    float* deg_inv = (float*)p;                 p += (size_t)N * 4;
    float* deg_rs  = (float*)p;                 p += (size_t)N * 4;
    float* X       = (float*)p;                 p += (size_t)N * 64 * 4;
    float* H       = (float*)p;                 p += (size_t)N * 64 * 4;
    int*   deg_cnt = (int*)p;                   p += (size_t)N * 4;
    int*   rowptr  = (int*)p;                   p += ((size_t)N + 1) * 4;
    int*   cursor  = (int*)p;                   p += (size_t)N * 4;
    int*   bsum    = (int*)p;                   p += 128 * 4;
    int*   csr_src = (int*)p;                   p += (size_t)E * 4;
    float* csr_w   = (float*)p;                 p += (size_t)E * 4;

    const int gNode = (N + BLK - 1) / BLK;
    const int gRows = (N + 3) / 4;        // gather: 4 nodes/block
    const int gGemm = (N + 127) / 128;    // gemm: 128 rows/block
    const int gEdge = (E + BLK - 1) / BLK;
    const int NB    = (N + SCAN_CHUNK - 1) / SCAN_CHUNK;

    // ---- degree + CSR build ----
    hipMemsetAsync(deg_cnt, 0, (size_t)N * sizeof(int), stream);
    count_deg_kernel<<<gEdge, BLK, 0, stream>>>(dst, deg_cnt, E);
    deg_finalize_kernel<<<gNode, BLK, 0, stream>>>(deg_cnt, deg_inv, deg_rs, N);
    scan_reduce_kernel<<<NB, BLK, 0, stream>>>(deg_cnt, bsum, N);
    scan_top_kernel<<<1, BLK, 0, stream>>>(bsum, NB);
    scan_final_kernel<<<NB, BLK, 0, stream>>>(deg_cnt, bsum, rowptr, cursor, N, E);
    csr_fill_kernel<<<gEdge, BLK, 0, stream>>>(src, dst, deg_rs, cursor, csr_src, csr_w, E);

    // ---- layer 1 ----
    gemm_lds_kernel<256, 0><<<gGemm, BLK, 0, stream>>>(x, W1, nullptr, H, N);
    gcn_gather_kernel<<<gRows, BLK, 0, stream>>>(H, rowptr, csr_src, csr_w, deg_rs, deg_inv, b1, X, N);

    // ---- layer 2 ----
    gemm_lds_kernel<64, 0><<<gGemm, BLK, 0, stream>>>(X, W2, nullptr, H, N);
    gcn_gather_kernel<<<gRows, BLK, 0, stream>>>(H, rowptr, csr_src, csr_w, deg_rs, deg_inv, b2, X, N);

    // ---- layer 3 ----
    gemm_lds_kernel<64, 0><<<gGemm, BLK, 0, stream>>>(X, W3, nullptr, H, N);
    gcn_gather_kernel<<<gRows, BLK, 0, stream>>>(H, rowptr, csr_src, csr_w, deg_rs, deg_inv, b3, X, N);

    // ---- projector ----
    gemm_lds_kernel<64, 1><<<gGemm, BLK, 0, stream>>>(X, Pw1, Pb1, H, N);
    gemm_lds_kernel<64, 2><<<gGemm, BLK, 0, stream>>>(H, Pw2, Pb2, (float*)d_out, N);
}